// Round 15
// baseline (198.821 us; speedup 1.0000x reference)
//
#include <hip/hip_runtime.h>

// GCN 2-layer forward for MI355X.
// out = D^-1/2 (A+I) D^-1/2 (X W) + b, twice, relu between.
// R2: CSR gather. R4: g bf16. R5: MFMA split-bf16 GEMM. R6-R8: bucketed CSR build.
// R9: XCD slicing FAILED. R10: scalar-addressed gather. R11: bf16 h2, 2-MFMA gemm2.
// R12: LDS-fused gather+gemm2 FAILED. R13: predicated unroll-8 gather (tail kill).
// R14: dinv deferred from gemm1 -> csr_and_gemm1 merged launch. CHUNK 2048.
// R15: gather unroll 8 -> 16: ~55% of nodes (deg<=16) finish in ONE serial
//      load-block (was 2-3); clamped slots hit L1 (same row). dr[] stays in
//      SGPRs (scalar chain), u[16] costs 16 VGPRs.

constexpr int KD = 128;      // inner dim of both GEMMs (Fin = Fh = 128)
constexpr int CHUNK = 2048;  // edges per block in scatter pass
constexpr int BCAP = 6144;   // slack capacity per bucket (mean 4096, sigma ~64)

using short8  = __attribute__((ext_vector_type(8))) short;
using float4v = __attribute__((ext_vector_type(4))) float;

// ---------------- bf16 helpers (storage = ushort, math = fp32) ----------------

__device__ __forceinline__ unsigned short f2bf(float f) {
    unsigned int u = __float_as_uint(f);
    u = (u + 0x7fffu + ((u >> 16) & 1u)) >> 16;  // round-to-nearest-even
    return (unsigned short)u;
}

__device__ __forceinline__ float2 bfpair(unsigned int u) {
    float2 f;
    f.x = __uint_as_float(u << 16);          // low short = first feature
    f.y = __uint_as_float(u & 0xffff0000u);  // high short = second feature
    return f;
}

__device__ __forceinline__ unsigned int packbf(float x, float y) {
    return (unsigned int)f2bf(x) | ((unsigned int)f2bf(y) << 16);
}

// split x = hi + lo (both bf16); subtraction is exact, |err| ~ 2^-17 |x|
__device__ __forceinline__ void bfsplit(float x, unsigned short& h, unsigned short& l) {
    h = f2bf(x);
    float fh = __uint_as_float((unsigned int)h << 16);
    l = f2bf(x - fh);
}

// ---------------- setup: W transpose+split (both layers) + gcur init ----------
__global__ __launch_bounds__(128) void setup(const float* __restrict__ W1,
                                             unsigned short* __restrict__ Wth1,
                                             unsigned short* __restrict__ Wtl1,
                                             const float* __restrict__ W2,
                                             unsigned short* __restrict__ Wth2,
                                             unsigned short* __restrict__ Wtl2,
                                             int* __restrict__ gcur) {
    int b = blockIdx.x;
    int n = threadIdx.x;
    int k = b & 127;
    if (b == 0) {
        gcur[n] = n * BCAP;
        gcur[n + 128] = (n + 128) * BCAP;
    }
    if (b < 128) {
        float w = W1[k * 128 + n];
        unsigned short h, l;
        bfsplit(w, h, l);
        Wth1[n * KD + k] = h;
        Wtl1[n * KD + k] = l;
    } else if (n < 64) {
        float w = W2[k * 64 + n];
        unsigned short h, l;
        bfsplit(w, h, l);
        Wth2[n * KD + k] = h;
        Wtl2[n * KD + k] = l;
    }
}

// ---------------- CSR build: edge scatter into slack buckets ----------------
// Packed record: (row<<16)|col (both < 50000 < 2^16).
__global__ __launch_bounds__(256) void bucket_scatter(const int* __restrict__ row,
                                                      const int* __restrict__ col,
                                                      int* gcur,
                                                      unsigned int* __restrict__ bpack,
                                                      int E) {
    __shared__ int lh[256];
    __shared__ int lbase[256];
    lh[threadIdx.x] = 0;
    __syncthreads();
    int base = blockIdx.x * CHUNK;
#pragma unroll
    for (int r = 0; r < CHUNK / 256; ++r) {
        int e = base + r * 256 + threadIdx.x;
        if (e < E) atomicAdd(&lh[col[e] >> 8], 1);
    }
    __syncthreads();
    int c0 = lh[threadIdx.x];
    lbase[threadIdx.x] = c0 ? atomicAdd(&gcur[threadIdx.x], c0) : 0;
    __syncthreads();
    lh[threadIdx.x] = 0;  // reuse as local running offset
    __syncthreads();
#pragma unroll
    for (int r = 0; r < CHUNK / 256; ++r) {
        int e = base + r * 256 + threadIdx.x;
        if (e < E) {
            int c = col[e];
            int b = c >> 8;
            int slot = lbase[b] + atomicAdd(&lh[b], 1);
            bpack[slot] = ((unsigned int)row[e] << 16) | (unsigned int)c;
        }
    }
}

// ------- MERGED: bucket_csr (blocks [0,NBUCKET)) + layer-1 GEMM (rest) -------
__global__ __launch_bounds__(256) void csr_and_gemm1(
        const unsigned int* __restrict__ bpack, const int* __restrict__ gcur,
        int* __restrict__ rowptr, float* __restrict__ dinv,
        unsigned short* __restrict__ srow, int N, int E, int NBUCKET,
        const float* __restrict__ X,
        const unsigned short* __restrict__ Wth,
        const unsigned short* __restrict__ Wtl,
        unsigned short* __restrict__ G) {
    __shared__ int s[256];
    __shared__ int lh[256];
    __shared__ int lcur[256];
    __shared__ int sh_bstart;

    if ((int)blockIdx.x < NBUCKET) {
        // ---------------- CSR build ----------------
        int b = blockIdx.x;
        int t = threadIdx.x;
        int cntb = gcur[t] - t * BCAP;
        s[t] = cntb;
        __syncthreads();
        for (int off = 1; off < 256; off <<= 1) {
            int tv = (t >= off) ? s[t - off] : 0;
            __syncthreads();
            s[t] += tv;
            __syncthreads();
        }
        if (t == b) sh_bstart = s[t] - cntb;  // exclusive prefix of this bucket
        if (b == 0 && t == 0) rowptr[N] = E;
        lh[t] = 0;
        __syncthreads();
        int bstart = sh_bstart;
        int nE = gcur[b] - b * BCAP;
        int base = b * BCAP;
        for (int i = t; i < nE; i += 256)
            atomicAdd(&lh[bpack[base + i] & 255], 1);
        __syncthreads();
        int v = lh[t];
        s[t] = v;
        __syncthreads();
        for (int off = 1; off < 256; off <<= 1) {
            int tv = (t >= off) ? s[t - off] : 0;
            __syncthreads();
            s[t] += tv;
            __syncthreads();
        }
        int myStart = bstart + s[t] - v;  // exclusive
        int node = (b << 8) + t;
        if (node < N) {
            rowptr[node] = myStart;
            dinv[node] = rsqrtf(1.0f + (float)v);
        }
        lcur[t] = myStart;
        __syncthreads();
        for (int i = t; i < nE; i += 256) {
            unsigned int p = bpack[base + i];
            int slot = atomicAdd(&lcur[p & 255], 1);
            srow[slot] = (unsigned short)(p >> 16);
        }
    } else {
        // ---------------- layer-1 GEMM (split-A, 3 MFMAs, no dinv) ----------
        constexpr int FOUT = 128, NT = 8;
        int wave = threadIdx.x >> 6;
        int lane = threadIdx.x & 63;
        int row0 = (((int)blockIdx.x - NBUCKET) * 4 + wave) * 16;
        if (row0 >= N) return;
        int m = lane & 15;
        int quad = lane >> 4;

        float4v acc[NT];
#pragma unroll
        for (int ct = 0; ct < NT; ++ct) acc[ct] = (float4v){0.f, 0.f, 0.f, 0.f};

        const float* xrow = X + (size_t)(row0 + m) * KD + quad * 8;

#pragma unroll
        for (int ks = 0; ks < 4; ++ks) {
            float4 xa = *(const float4*)(xrow + ks * 32);
            float4 xb = *(const float4*)(xrow + ks * 32 + 4);
            float xs[8] = {xa.x, xa.y, xa.z, xa.w, xb.x, xb.y, xb.z, xb.w};
            short8 ah, al;
#pragma unroll
            for (int j = 0; j < 8; ++j) {
                unsigned short h, l;
                bfsplit(xs[j], h, l);
                ah[j] = (short)h;
                al[j] = (short)l;
            }
            int koff = ks * 32 + quad * 8;
#pragma unroll
            for (int ct = 0; ct < NT; ++ct) {
                short8 bh = *(const short8*)(Wth + (size_t)(ct * 16 + m) * KD + koff);
                short8 bl = *(const short8*)(Wtl + (size_t)(ct * 16 + m) * KD + koff);
                acc[ct] = __builtin_amdgcn_mfma_f32_16x16x32_bf16(ah, bh, acc[ct], 0, 0, 0);
                acc[ct] = __builtin_amdgcn_mfma_f32_16x16x32_bf16(al, bh, acc[ct], 0, 0, 0);
                acc[ct] = __builtin_amdgcn_mfma_f32_16x16x32_bf16(ah, bl, acc[ct], 0, 0, 0);
            }
        }

#pragma unroll
        for (int r = 0; r < 4; ++r) {
            int row = row0 + quad * 4 + r;
#pragma unroll
            for (int ct = 0; ct < NT; ++ct) {
                G[(size_t)row * FOUT + ct * 16 + m] = f2bf(acc[ct][r]);
            }
        }
    }
}

// -------- layer-2 GEMM (bf16 in): G = bf16(dinv*(H@W)), 2 MFMAs, no A-split --
__global__ __launch_bounds__(256) void gemm_mfma2(const unsigned short* __restrict__ H,
                                                  const unsigned short* __restrict__ Wth,
                                                  const unsigned short* __restrict__ Wtl,
                                                  const float* __restrict__ dinv,
                                                  unsigned short* __restrict__ G, int N) {
    constexpr int FOUT = 64, NT = 4;
    int wave = threadIdx.x >> 6;
    int lane = threadIdx.x & 63;
    int row0 = (blockIdx.x * 4 + wave) * 16;
    if (row0 >= N) return;
    int m = lane & 15;
    int quad = lane >> 4;

    float4v acc[NT];
#pragma unroll
    for (int ct = 0; ct < NT; ++ct) acc[ct] = (float4v){0.f, 0.f, 0.f, 0.f};

    const unsigned short* hrow = H + (size_t)(row0 + m) * KD + quad * 8;

#pragma unroll
    for (int ks = 0; ks < 4; ++ks) {
        short8 a = *(const short8*)(hrow + ks * 32);
        int koff = ks * 32 + quad * 8;
#pragma unroll
        for (int ct = 0; ct < NT; ++ct) {
            short8 bh = *(const short8*)(Wth + (size_t)(ct * 16 + m) * KD + koff);
            short8 bl = *(const short8*)(Wtl + (size_t)(ct * 16 + m) * KD + koff);
            acc[ct] = __builtin_amdgcn_mfma_f32_16x16x32_bf16(a, bh, acc[ct], 0, 0, 0);
            acc[ct] = __builtin_amdgcn_mfma_f32_16x16x32_bf16(a, bl, acc[ct], 0, 0, 0);
        }
    }

#pragma unroll
    for (int r = 0; r < 4; ++r) {
        int row = row0 + quad * 4 + r;
        float s = dinv[row];
#pragma unroll
        for (int ct = 0; ct < 4; ++ct) {
            G[(size_t)row * FOUT + ct * 16 + m] = f2bf(acc[ct][r] * s);
        }
    }
}

// ---------------- CSR gather + finalize (fused), bf16 operand ----------------
// F=128: one wave per node, scalar (readfirstlane) row base. Predicated
// UNROLL-16: deg<=16 nodes issue all loads in one block (no serial chain);
// clamped slots reload row[end-1] -> L1 hit. dinv folded (g1 unscaled).
template <bool RELU>
__global__ __launch_bounds__(256) void gather128(const int* __restrict__ rowptr,
                                                 const unsigned short* __restrict__ srow,
                                                 const unsigned int* __restrict__ G,  // bf16x2
                                                 const float* __restrict__ dinv,
                                                 const float* __restrict__ bias,
                                                 unsigned int* __restrict__ H2,  // bf16x2 out
                                                 int N) {
    int node = (blockIdx.x * 256 + threadIdx.x) >> 6;
    int lane = threadIdx.x & 63;
    if (node >= N) return;
    int beg = rowptr[node];
    int end = rowptr[node + 1];
    float dn = dinv[node];

    float ax, ay;
    {
        float2 s0 = bfpair(G[(size_t)node * 64 + lane]);  // self-loop (x dinv[n])
        ax = s0.x * dn; ay = s0.y * dn;
    }

    for (int e = beg; e < end; e += 16) {
        unsigned int u[16];
        float dr[16];
#pragma unroll
        for (int j = 0; j < 16; ++j) {
            int idx = e + j;
            idx = (idx < end) ? idx : (end - 1);  // uniform clamp (end>beg here)
            int r = __builtin_amdgcn_readfirstlane((int)srow[idx]);
            dr[j] = dinv[r];                      // scalar chain -> SGPR
            const unsigned int* p = G + (size_t)r * 64;  // uniform base (SGPR)
            u[j] = p[lane];
        }
        float sx = 0.f, sy = 0.f;
#pragma unroll
        for (int j = 0; j < 16; ++j) {
            unsigned int uv = (e + j < end) ? u[j] : 0u;  // zero-mask invalid
            float2 v = bfpair(uv);
            sx = fmaf(dr[j], v.x, sx);
            sy = fmaf(dr[j], v.y, sy);
        }
        ax += sx; ay += sy;
    }
    float2 bv = ((const float2*)bias)[lane];
    float ox = ax * dn + bv.x;
    float oy = ay * dn + bv.y;
    if (RELU) { ox = fmaxf(ox, 0.f); oy = fmaxf(oy, 0.f); }
    __builtin_nontemporal_store(packbf(ox, oy), &H2[(size_t)node * 64 + lane]);
}

// F=64: half-wave per node (32 lanes x bf16x2 = 128B row), predicated unroll-16,
// fp32 nt out. g2 pre-scaled by dinv (gemm2 epilogue).
template <bool RELU>
__global__ __launch_bounds__(256) void gather64(const int* __restrict__ rowptr,
                                                const unsigned short* __restrict__ srow,
                                                const unsigned int* __restrict__ G,  // bf16x2
                                                const float* __restrict__ dinv,
                                                const float* __restrict__ bias,
                                                float* __restrict__ O, int N) {
    int tid = blockIdx.x * 256 + threadIdx.x;
    int node = tid >> 5;          // half-wave per node
    int lane = threadIdx.x & 31;
    if (node >= N) return;
    int beg = rowptr[node];
    int end = rowptr[node + 1];

    float2 s0 = bfpair(G[(size_t)node * 32 + lane]);  // self-loop
    float ax = s0.x, ay = s0.y;

    for (int e = beg; e < end; e += 16) {
        unsigned int u[16];
#pragma unroll
        for (int j = 0; j < 16; ++j) {
            int idx = e + j;
            idx = (idx < end) ? idx : (end - 1);
            int r = (int)srow[idx];
            u[j] = G[(size_t)r * 32 + lane];
        }
        float sx = 0.f, sy = 0.f;
#pragma unroll
        for (int j = 0; j < 16; ++j) {
            unsigned int uv = (e + j < end) ? u[j] : 0u;
            float2 v = bfpair(uv);
            sx += v.x; sy += v.y;
        }
        ax += sx; ay += sy;
    }
    float s = dinv[node];
    float2 bv = ((const float2*)bias)[lane];
    float ox = ax * s + bv.x;
    float oy = ay * s + bv.y;
    if (RELU) { ox = fmaxf(ox, 0.f); oy = fmaxf(oy, 0.f); }
    float2 o = make_float2(ox, oy);
    unsigned long long p;
    __builtin_memcpy(&p, &o, 8);
    __builtin_nontemporal_store(p, (unsigned long long*)&((float2*)O)[(size_t)node * 32 + lane]);
}

extern "C" void kernel_launch(void* const* d_in, const int* in_sizes, int n_in,
                              void* d_out, int out_size, void* d_ws, size_t ws_size,
                              hipStream_t stream) {
    const float* x  = (const float*)d_in[0];
    const int*   ei = (const int*)d_in[1];   // int32
    const float* W1 = (const float*)d_in[2];
    const float* b1 = (const float*)d_in[3];
    const float* W2 = (const float*)d_in[4];
    const float* b2 = (const float*)d_in[5];
    float* out = (float*)d_out;

    int N = in_sizes[0] / 128;
    int E = in_sizes[1] / 2;
    const int* row = ei;       // edge_index[0]
    const int* col = ei + E;   // edge_index[1]

    // Workspace layout (all regions written before read each call)
    char* ws = (char*)d_ws;
    float* dinv   = (float*)(ws + 0x000000);             // 200 KB
    int*   rowptr = (int*)  (ws + 0x080000);             // 200 KB + 4
    int*   gcur   = (int*)  (ws + 0x0F9000);             // 1 KB
    unsigned short* srow = (unsigned short*)(ws + 0x100000);   // 1.6 MB
    unsigned short* g1 = (unsigned short*)(ws + 0x440000);     // 12.8 MB
    unsigned short* wth1 = (unsigned short*)(ws + 0x10C0000);  // 32 KB
    unsigned short* wtl1 = (unsigned short*)(ws + 0x10D0000);  // 32 KB
    unsigned short* wth2 = (unsigned short*)(ws + 0x10E0000);  // 16 KB
    unsigned short* wtl2 = (unsigned short*)(ws + 0x10F0000);  // 16 KB
    unsigned short* h2 = (unsigned short*)(ws + 0x1200000);    // 12.8 MB (bf16)
    unsigned short* g2 = (unsigned short*)(ws + 0x2C00000);    // 6.4 MB
    // Packed slack bucket buffer (256 x BCAP uints = 6.29 MB) overlaps h2's
    // region: consumed by csr_and_gemm1 before gather128 first writes h2.
    unsigned int* bpack = (unsigned int*)(ws + 0x1200000);     // 6.29 MB

    int NB_BKT  = (E + CHUNK - 1) / CHUNK;   // 391
    int NBUCKET = (N + 255) / 256;           // 196
    int NB_GEMM1 = (N + 63) / 64;            // 782

    // ---- setup + scatter + merged CSR/GEMM1 (3 launches) ----
    setup<<<256, 128, 0, stream>>>(W1, wth1, wtl1, W2, wth2, wtl2, gcur);
    bucket_scatter<<<NB_BKT, 256, 0, stream>>>(row, col, gcur, bpack, E);
    csr_and_gemm1<<<NBUCKET + NB_GEMM1, 256, 0, stream>>>(
        bpack, gcur, rowptr, dinv, srow, N, E, NBUCKET, x, wth1, wtl1, g1);

    int nb;
    // ---- layer-1 gather (dinv folded in) ----
    nb = (N + 3) / 4;    // one wave per node
    gather128<true><<<nb, 256, 0, stream>>>(rowptr, srow, (const unsigned int*)g1,
                                            dinv, b1, (unsigned int*)h2, N);

    // ---- layer 2 (F=64, no relu) ----
    nb = (N + 63) / 64;
    gemm_mfma2<<<nb, 256, 0, stream>>>(h2, wth2, wtl2, dinv, g2, N);
    nb = (N + 7) / 8;    // half-wave per node
    gather64<false><<<nb, 256, 0, stream>>>(rowptr, srow, (const unsigned int*)g2,
                                            dinv, b2, out, N);
}